// Round 1
// baseline (27464.868 us; speedup 1.0000x reference)
//
#include <hip/hip_runtime.h>
#include <math.h>

// Problem constants (from reference setup_inputs)
#define NN    50000     // nodes
#define EPOS  400000    // positive edges
#define ROWS  800000    // 2E total rows
#define DIM   128       // node feature dim
#define D2    256       // 2*DIM (edge feat)
#define H1C   256       // hidden 1
#define H2C   128       // hidden 2
#define TILE  32        // edges per block
#define PAD   264       // LDS row stride (words), multiple of 4, breaks pow2

__global__ __launch_bounds__(256, 4) void lp_fused(
    const float* __restrict__ x,
    const int*   __restrict__ ei,
    const int*   __restrict__ nei,
    const float* __restrict__ w1, const float* __restrict__ b1,
    const float* __restrict__ g1, const float* __restrict__ be1,
    const float* __restrict__ w2, const float* __restrict__ b2,
    const float* __restrict__ g2, const float* __restrict__ be2,
    const float* __restrict__ w3, const float* __restrict__ b3,
    float* __restrict__ out)
{
    __shared__ float lds[TILE][PAD];

    const int t   = threadIdx.x;
    const int e   = t >> 3;      // edge within tile (0..31)
    const int jg  = t & 7;       // column group (0..7)
    const int rowBase = blockIdx.x * TILE;
    const int row = rowBase + e;

    // ---------- Stage gathered edge features into LDS ----------
    // thread (e, p): p = jg covers 32 contiguous floats of feat[e]
    {
        int r = row;
        int src, dst;
        if (r < EPOS) { src = ei[r];        dst = ei[EPOS + r]; }
        else          { src = nei[r - EPOS]; dst = nei[r]; }   // nei[E + (r-E)] == nei[r]
        const int p = jg;
        const float* base = (p < 4) ? (x + src * DIM + p * 32)
                                    : (x + dst * DIM + (p - 4) * 32);
        const float4* b4 = (const float4*)base;
        #pragma unroll
        for (int s = 0; s < 8; ++s) {
            float4 v = b4[s];
            *(float4*)&lds[e][p * 32 + s * 4] = v;
        }
    }
    __syncthreads();

    // ---------- GEMM1: h1[e][j] = feat[e][:] @ w1[:, j],  j in [j0, j0+32) ----------
    float acc[32];
    #pragma unroll
    for (int i = 0; i < 32; ++i) acc[i] = 0.f;
    const int j0 = jg * 32;

    for (int k4 = 0; k4 < D2 / 4; ++k4) {
        float4 a4 = *(const float4*)&lds[e][k4 * 4];
        float av[4] = {a4.x, a4.y, a4.z, a4.w};
        #pragma unroll
        for (int kk = 0; kk < 4; ++kk) {
            const int k = k4 * 4 + kk;
            const float a = av[kk];
            const float4* wr = (const float4*)(w1 + k * H1C + j0);
            #pragma unroll
            for (int ii = 0; ii < 8; ++ii) {
                float4 wv = wr[ii];
                acc[ii * 4 + 0] += a * wv.x;
                acc[ii * 4 + 1] += a * wv.y;
                acc[ii * 4 + 2] += a * wv.z;
                acc[ii * 4 + 3] += a * wv.w;
            }
        }
    }

    // bias + layernorm stats (256 values spread over 8 lanes of this edge)
    float s1 = 0.f, s2 = 0.f;
    #pragma unroll
    for (int i = 0; i < 32; ++i) {
        float h = acc[i] + b1[j0 + i];
        acc[i] = h;
        s1 += h; s2 += h * h;
    }
    #pragma unroll
    for (int m = 1; m < 8; m <<= 1) {
        s1 += __shfl_xor(s1, m, 8);
        s2 += __shfl_xor(s2, m, 8);
    }
    float mean = s1 * (1.f / 256.f);
    float var  = s2 * (1.f / 256.f) - mean * mean;
    float rstd = rsqrtf(var + 1e-5f);

    __syncthreads();   // all threads done reading feat; reuse buffer for h1
    #pragma unroll
    for (int i = 0; i < 32; ++i) {
        float h = (acc[i] - mean) * rstd * g1[j0 + i] + be1[j0 + i];
        lds[e][j0 + i] = fmaxf(h, 0.f);
    }
    __syncthreads();

    // ---------- GEMM2: h2[e][q] = h1[e][:] @ w2[:, q],  q in [q0, q0+16) ----------
    float acc2[16];
    #pragma unroll
    for (int i = 0; i < 16; ++i) acc2[i] = 0.f;
    const int q0 = jg * 16;

    for (int k4 = 0; k4 < H1C / 4; ++k4) {
        float4 a4 = *(const float4*)&lds[e][k4 * 4];
        float av[4] = {a4.x, a4.y, a4.z, a4.w};
        #pragma unroll
        for (int kk = 0; kk < 4; ++kk) {
            const int k = k4 * 4 + kk;
            const float a = av[kk];
            const float4* wr = (const float4*)(w2 + k * H2C + q0);
            #pragma unroll
            for (int ii = 0; ii < 4; ++ii) {
                float4 wv = wr[ii];
                acc2[ii * 4 + 0] += a * wv.x;
                acc2[ii * 4 + 1] += a * wv.y;
                acc2[ii * 4 + 2] += a * wv.z;
                acc2[ii * 4 + 3] += a * wv.w;
            }
        }
    }

    // bias + layernorm over 128
    s1 = 0.f; s2 = 0.f;
    #pragma unroll
    for (int i = 0; i < 16; ++i) {
        float h = acc2[i] + b2[q0 + i];
        acc2[i] = h;
        s1 += h; s2 += h * h;
    }
    #pragma unroll
    for (int m = 1; m < 8; m <<= 1) {
        s1 += __shfl_xor(s1, m, 8);
        s2 += __shfl_xor(s2, m, 8);
    }
    mean = s1 * (1.f / 128.f);
    var  = s2 * (1.f / 128.f) - mean * mean;
    rstd = rsqrtf(var + 1e-5f);

    // ---------- final dot with w3 + sigmoid ----------
    float zp = 0.f;
    #pragma unroll
    for (int i = 0; i < 16; ++i) {
        float h = (acc2[i] - mean) * rstd * g2[q0 + i] + be2[q0 + i];
        h = fmaxf(h, 0.f);
        zp += h * w3[q0 + i];
    }
    #pragma unroll
    for (int m = 1; m < 8; m <<= 1) zp += __shfl_xor(zp, m, 8);

    if (jg == 0) {
        float z = zp + b3[0];
        out[row] = 1.f / (1.f + expf(-z));
    }
    if (jg == 1) {
        out[ROWS + row] = (row < EPOS) ? 1.f : 0.f;
    }
}

extern "C" void kernel_launch(void* const* d_in, const int* in_sizes, int n_in,
                              void* d_out, int out_size, void* d_ws, size_t ws_size,
                              hipStream_t stream) {
    const float* x   = (const float*)d_in[0];
    const int*   ei  = (const int*)d_in[1];
    // d_in[2] = batch (unused at inference; consumed only by setup-time sampler)
    const int*   nei = (const int*)d_in[3];
    const float* w1  = (const float*)d_in[4];
    const float* b1  = (const float*)d_in[5];
    const float* g1  = (const float*)d_in[6];
    const float* be1 = (const float*)d_in[7];
    const float* w2  = (const float*)d_in[8];
    const float* b2  = (const float*)d_in[9];
    const float* g2  = (const float*)d_in[10];
    const float* be2 = (const float*)d_in[11];
    const float* w3  = (const float*)d_in[12];
    const float* b3  = (const float*)d_in[13];
    float* out = (float*)d_out;

    dim3 grid(ROWS / TILE);   // 25000 blocks
    dim3 block(256);
    hipLaunchKernelGGL(lp_fused, grid, block, 0, stream,
                       x, ei, nei, w1, b1, g1, be1, w2, b2, g2, be2, w3, b3, out);
}

// Round 2
// 599.644 us; speedup vs baseline: 45.8019x; 45.8019x over previous
//
#include <hip/hip_runtime.h>
#include <math.h>
#include <stdint.h>

// Problem constants
#define NN    50000
#define EPOS  400000
#define ROWS  800000
#define DIM   128
#define D2    256
#define H1C   256
#define H2C   128
#define MT    128           // edge rows per block (MFMA kernel)
#define NTH   512           // 8 waves

typedef __bf16 bf16;
typedef __bf16 bf16x8 __attribute__((ext_vector_type(8)));
typedef float  f32x4  __attribute__((ext_vector_type(4)));

// ---- workspace element offsets (bf16 elements) ----
#define XB_E    0
#define XB_N    (NN*DIM)            // 6,400,000  x as bf16 [node][128]
#define W1T_E   XB_N
#define W1T_N   (H1C*D2)            // 65,536     w1T [n=256][k=256]
#define W2T_E   (XB_N + W1T_N)
#define W2T_N   (H2C*H1C)           // 32,768     w2T [n=128][k=256]
#define WS_NEEDED ((size_t)(XB_N + W1T_N + W2T_N) * 2)   // 12,996,608 B

// ---- LDS byte offsets (total exactly 160 KiB) ----
#define AB0   0        // A chunk buf0 [128 rows][64 k] bf16 = 16 KB
#define AB1   16384
#define BB0   32768    // B chunk buf0 [256 n][64 k] bf16 = 32 KB
#define BB1   65536
#define H1O   98304    // h1 [128][256] bf16 = 64 KB (swizzled, 512B rows)
#define SCR   65536    // 4 KB LN scratch  (BB1 area, phase-disjoint)
#define SCR2  69632    // 2 KB z scratch
#define SMEM_BYTES 163840

__device__ __forceinline__ void gll16(const void* g, void* l) {
    __builtin_amdgcn_global_load_lds(
        (const __attribute__((address_space(1))) void*)g,
        (__attribute__((address_space(3))) void*)l, 16, 0, 0);
}

// ===================== pre-convert kernel =====================
__global__ void preconv(const float* __restrict__ x, const float* __restrict__ w1,
                        const float* __restrict__ w2, bf16* __restrict__ ws) {
    int i = blockIdx.x * 256 + threadIdx.x;
    if (i < XB_N) { ws[i] = (bf16)x[i]; return; }
    i -= XB_N;
    if (i < W1T_N) {            // w1T[n][k] = w1[k][n]
        int n = i >> 8, k = i & 255;
        ws[W1T_E + i] = (bf16)w1[k * H1C + n];
        return;
    }
    i -= W1T_N;
    if (i < W2T_N) {            // w2T[n][k] = w2[k][n]
        int n = i >> 8, k = i & 255;
        ws[W2T_E + i] = (bf16)w2[k * H2C + n];
    }
}

// ===================== fused MFMA kernel =====================
__global__ __launch_bounds__(NTH, 2) void lp_mfma(
    const bf16* __restrict__ xb, const bf16* __restrict__ w1t, const bf16* __restrict__ w2t,
    const int*  __restrict__ ei, const int* __restrict__ nei,
    const float* __restrict__ b1, const float* __restrict__ g1, const float* __restrict__ be1,
    const float* __restrict__ b2, const float* __restrict__ g2, const float* __restrict__ be2,
    const float* __restrict__ w3, const float* __restrict__ b3,
    float* __restrict__ out)
{
    extern __shared__ char smem[];
    const int tid  = threadIdx.x;
    const int lane = tid & 63;
    const int w    = tid >> 6;        // wave 0..7
    const int wm   = w >> 2;          // M half (0..1)
    const int wn   = w & 3;           // N quarter (0..3)
    const int gr0  = blockIdx.x * MT;
    const int l15  = lane & 15;
    const int l4   = lane >> 4;       // 0..3

    // --- staging: A chunk (gathered feat K-slice), 16 gll of 1KB ---
    auto stageA = [&](int c, int abase) {
        const int  xoffb   = (c & 1) << 7;   // byte offset within node's 256B row
        const bool dstside = (c >= 2);
        #pragma unroll
        for (int ii = 0; ii < 2; ++ii) {
            const int i = (w << 1) + ii;
            uint32_t doff = (uint32_t)(i << 10) + (uint32_t)(lane << 4);
            uint32_t loff = doff ^ (((doff >> 7) & 7u) << 4);   // inverse swizzle
            int row = loff >> 7;
            int inb = loff & 127;
            int gr  = gr0 + row;
            int node;
            if (!dstside) node = (gr < EPOS) ? ei[gr]        : nei[gr - EPOS];
            else          node = (gr < EPOS) ? ei[EPOS + gr] : nei[gr];
            const char* src = (const char*)xb + (((size_t)node) << 8) + xoffb + inb;
            gll16(src, smem + abase + (i << 10));
        }
    };
    // --- staging: B chunk (w1T K-slice), 32 gll of 1KB ---
    auto stageB = [&](int c, int bbase) {
        const int k0b = c << 7;
        #pragma unroll
        for (int ii = 0; ii < 4; ++ii) {
            const int i = (w << 2) + ii;
            uint32_t doff = (uint32_t)(i << 10) + (uint32_t)(lane << 4);
            uint32_t loff = doff ^ (((doff >> 7) & 7u) << 4);
            int n   = loff >> 7;
            int inb = loff & 127;
            const char* src = (const char*)w1t + (((size_t)n) << 9) + k0b + inb;
            gll16(src, smem + bbase + (i << 10));
        }
    };

    // ================= GEMM1: feat[128x256] @ w1[256x256] =================
    f32x4 acc1[4][4] = {};
    stageA(0, AB0); stageB(0, BB0);
    __syncthreads();

    int abase = AB0, bbase = BB0;
    #pragma unroll
    for (int c = 0; c < 4; ++c) {
        const int nab = (c & 1) ? AB0 : AB1;
        const int nbb = (c & 1) ? BB0 : BB1;
        if (c < 3) { stageA(c + 1, nab); stageB(c + 1, nbb); }
        #pragma unroll
        for (int ks = 0; ks < 2; ++ks) {
            bf16x8 af[4], bfx[4];
            #pragma unroll
            for (int mi = 0; mi < 4; ++mi) {
                int row = (wm << 6) + (mi << 4) + l15;
                uint32_t byte = (uint32_t)(row << 7) + (uint32_t)(ks << 6) + (uint32_t)(l4 << 4);
                byte ^= ((byte >> 7) & 7u) << 4;
                af[mi] = *(const bf16x8*)(smem + abase + byte);
            }
            #pragma unroll
            for (int ni = 0; ni < 4; ++ni) {
                int n = (wn << 6) + (ni << 4) + l15;
                uint32_t byte = (uint32_t)(n << 7) + (uint32_t)(ks << 6) + (uint32_t)(l4 << 4);
                byte ^= ((byte >> 7) & 7u) << 4;
                bfx[ni] = *(const bf16x8*)(smem + bbase + byte);
            }
            #pragma unroll
            for (int mi = 0; mi < 4; ++mi)
                #pragma unroll
                for (int ni = 0; ni < 4; ++ni)
                    acc1[mi][ni] = __builtin_amdgcn_mfma_f32_16x16x32_bf16(
                        af[mi], bfx[ni], acc1[mi][ni], 0, 0, 0);
        }
        __syncthreads();
        abase = nab; bbase = nbb;
    }

    // --- issue w2T staging (64KB into LDS[0..64K)) to overlap with LN1 ---
    #pragma unroll
    for (int ii = 0; ii < 8; ++ii) {
        const int i = (w << 3) + ii;
        uint32_t doff = (uint32_t)(i << 10) + (uint32_t)(lane << 4);
        uint32_t loff = doff ^ (((doff >> 9) & 7u) << 4);
        gll16((const char*)w2t + loff, smem + (i << 10));
    }

    // ================= LN1 + ReLU -> h1 (LDS) =================
    float cb1[4], cg1[4], cbe1[4];
    #pragma unroll
    for (int ni = 0; ni < 4; ++ni) {
        int col = (wn << 6) + (ni << 4) + l15;
        cb1[ni] = b1[col]; cg1[ni] = g1[col]; cbe1[ni] = be1[col];
    }
    #pragma unroll
    for (int mi = 0; mi < 4; ++mi) {
        #pragma unroll
        for (int j = 0; j < 4; ++j) {
            float s1 = 0.f, s2 = 0.f;
            #pragma unroll
            for (int ni = 0; ni < 4; ++ni) {
                float v = acc1[mi][ni][j] + cb1[ni];
                acc1[mi][ni][j] = v;
                s1 += v; s2 += v * v;
            }
            #pragma unroll
            for (int m = 1; m < 16; m <<= 1) { s1 += __shfl_xor(s1, m); s2 += __shfl_xor(s2, m); }
            if (l15 == 0) {
                int row = (wm << 6) + (mi << 4) + (l4 << 2) + j;
                *(float2*)(smem + SCR + (row << 5) + (wn << 3)) = make_float2(s1, s2);
            }
        }
    }
    __syncthreads();
    #pragma unroll
    for (int mi = 0; mi < 4; ++mi) {
        #pragma unroll
        for (int j = 0; j < 4; ++j) {
            int row = (wm << 6) + (mi << 4) + (l4 << 2) + j;
            f32x4 p0 = *(const f32x4*)(smem + SCR + (row << 5));
            f32x4 p1 = *(const f32x4*)(smem + SCR + (row << 5) + 16);
            float s1 = p0[0] + p0[2] + p1[0] + p1[2];
            float s2 = p0[1] + p0[3] + p1[1] + p1[3];
            float mean = s1 * (1.f / 256.f);
            float var  = s2 * (1.f / 256.f) - mean * mean;
            float rstd = rsqrtf(var + 1e-5f);
            #pragma unroll
            for (int ni = 0; ni < 4; ++ni) {
                int col = (wn << 6) + (ni << 4) + l15;
                float h = (acc1[mi][ni][j] - mean) * rstd * cg1[ni] + cbe1[ni];
                h = fmaxf(h, 0.f);
                uint32_t byte = (uint32_t)(row << 9) + (uint32_t)(col << 1);
                byte ^= ((byte >> 9) & 7u) << 4;
                *(bf16*)(smem + H1O + byte) = (bf16)h;
            }
        }
    }
    __syncthreads();   // h1 ready; w2T gll drained by barrier's vmcnt(0)

    // ================= GEMM2: h1[128x256] @ w2[256x128] =================
    f32x4 acc2[4][2] = {};
    #pragma unroll
    for (int ks = 0; ks < 8; ++ks) {
        bf16x8 a2[4], b2f[2];
        #pragma unroll
        for (int mi = 0; mi < 4; ++mi) {
            int row = (wm << 6) + (mi << 4) + l15;
            uint32_t byte = (uint32_t)(row << 9) + (uint32_t)(ks << 6) + (uint32_t)(l4 << 4);
            byte ^= ((byte >> 9) & 7u) << 4;
            a2[mi] = *(const bf16x8*)(smem + H1O + byte);
        }
        #pragma unroll
        for (int ni = 0; ni < 2; ++ni) {
            int n = (wn << 5) + (ni << 4) + l15;
            uint32_t byte = (uint32_t)(n << 9) + (uint32_t)(ks << 6) + (uint32_t)(l4 << 4);
            byte ^= ((byte >> 9) & 7u) << 4;
            b2f[ni] = *(const bf16x8*)(smem + byte);
        }
        #pragma unroll
        for (int mi = 0; mi < 4; ++mi)
            #pragma unroll
            for (int ni = 0; ni < 2; ++ni)
                acc2[mi][ni] = __builtin_amdgcn_mfma_f32_16x16x32_bf16(
                    a2[mi], b2f[ni], acc2[mi][ni], 0, 0, 0);
    }

    // ================= LN2 + ReLU + w3 dot + sigmoid =================
    float cb2[2], cg2[2], cbe2[2], cw3[2];
    #pragma unroll
    for (int ni = 0; ni < 2; ++ni) {
        int col = (wn << 5) + (ni << 4) + l15;
        cb2[ni] = b2[col]; cg2[ni] = g2[col]; cbe2[ni] = be2[col]; cw3[ni] = w3[col];
    }
    const float b3s = b3[0];

    #pragma unroll
    for (int mi = 0; mi < 4; ++mi) {
        #pragma unroll
        for (int j = 0; j < 4; ++j) {
            float s1 = 0.f, s2 = 0.f;
            #pragma unroll
            for (int ni = 0; ni < 2; ++ni) {
                float v = acc2[mi][ni][j] + cb2[ni];
                acc2[mi][ni][j] = v;
                s1 += v; s2 += v * v;
            }
            #pragma unroll
            for (int m = 1; m < 16; m <<= 1) { s1 += __shfl_xor(s1, m); s2 += __shfl_xor(s2, m); }
            if (l15 == 0) {
                int row = (wm << 6) + (mi << 4) + (l4 << 2) + j;
                *(float2*)(smem + SCR + (row << 5) + (wn << 3)) = make_float2(s1, s2);
            }
        }
    }
    __syncthreads();
    #pragma unroll
    for (int mi = 0; mi < 4; ++mi) {
        #pragma unroll
        for (int j = 0; j < 4; ++j) {
            int row = (wm << 6) + (mi << 4) + (l4 << 2) + j;
            f32x4 p0 = *(const f32x4*)(smem + SCR + (row << 5));
            f32x4 p1 = *(const f32x4*)(smem + SCR + (row << 5) + 16);
            float s1 = p0[0] + p0[2] + p1[0] + p1[2];
            float s2 = p0[1] + p0[3] + p1[1] + p1[3];
            float mean = s1 * (1.f / 128.f);
            float var  = s2 * (1.f / 128.f) - mean * mean;
            float rstd = rsqrtf(var + 1e-5f);
            float zp = 0.f;
            #pragma unroll
            for (int ni = 0; ni < 2; ++ni) {
                float h = (acc2[mi][ni][j] - mean) * rstd * cg2[ni] + cbe2[ni];
                h = fmaxf(h, 0.f);
                zp += h * cw3[ni];
            }
            #pragma unroll
            for (int m = 1; m < 16; m <<= 1) zp += __shfl_xor(zp, m);
            if (l15 == 0)
                *(float*)(smem + SCR2 + (row << 4) + (wn << 2)) = zp;
        }
    }
    __syncthreads();
    #pragma unroll
    for (int mi = 0; mi < 4; ++mi) {
        #pragma unroll
        for (int j = 0; j < 4; ++j) {
            int row = (wm << 6) + (mi << 4) + (l4 << 2) + j;
            if (l15 == 0) {
                f32x4 zv = *(const f32x4*)(smem + SCR2 + (row << 4));
                float z = zv[0] + zv[1] + zv[2] + zv[3] + b3s;
                out[gr0 + row] = 1.f / (1.f + expf(-z));
            }
            if (l15 == 1) {
                int grr = gr0 + row;
                out[ROWS + grr] = (grr < EPOS) ? 1.f : 0.f;
            }
        }
    }
}

// ===================== fallback (round-1 kernel, known correct) =====================
#define TILE  32
#define PAD   264
__global__ __launch_bounds__(256, 4) void lp_fused(
    const float* __restrict__ x, const int* __restrict__ ei, const int* __restrict__ nei,
    const float* __restrict__ w1, const float* __restrict__ b1,
    const float* __restrict__ g1, const float* __restrict__ be1,
    const float* __restrict__ w2, const float* __restrict__ b2,
    const float* __restrict__ g2, const float* __restrict__ be2,
    const float* __restrict__ w3, const float* __restrict__ b3,
    float* __restrict__ out)
{
    __shared__ float lds[TILE][PAD];
    const int t = threadIdx.x, e = t >> 3, jg = t & 7;
    const int row = blockIdx.x * TILE + e;
    {
        int src, dst;
        if (row < EPOS) { src = ei[row];         dst = ei[EPOS + row]; }
        else            { src = nei[row - EPOS]; dst = nei[row]; }
        const float* base = (jg < 4) ? (x + src * DIM + jg * 32) : (x + dst * DIM + (jg - 4) * 32);
        const float4* b4 = (const float4*)base;
        #pragma unroll
        for (int s = 0; s < 8; ++s) *(float4*)&lds[e][jg * 32 + s * 4] = b4[s];
    }
    __syncthreads();
    float acc[32];
    #pragma unroll
    for (int i = 0; i < 32; ++i) acc[i] = 0.f;
    const int j0 = jg * 32;
    for (int k4 = 0; k4 < D2 / 4; ++k4) {
        float4 a4 = *(const float4*)&lds[e][k4 * 4];
        float av[4] = {a4.x, a4.y, a4.z, a4.w};
        #pragma unroll
        for (int kk = 0; kk < 4; ++kk) {
            const float a = av[kk];
            const float4* wr = (const float4*)(w1 + (k4 * 4 + kk) * H1C + j0);
            #pragma unroll
            for (int ii = 0; ii < 8; ++ii) {
                float4 wv = wr[ii];
                acc[ii*4+0] += a*wv.x; acc[ii*4+1] += a*wv.y; acc[ii*4+2] += a*wv.z; acc[ii*4+3] += a*wv.w;
            }
        }
    }
    float s1 = 0.f, s2 = 0.f;
    #pragma unroll
    for (int i = 0; i < 32; ++i) { float h = acc[i] + b1[j0+i]; acc[i] = h; s1 += h; s2 += h*h; }
    #pragma unroll
    for (int m = 1; m < 8; m <<= 1) { s1 += __shfl_xor(s1, m, 8); s2 += __shfl_xor(s2, m, 8); }
    float mean = s1 * (1.f/256.f), var = s2 * (1.f/256.f) - mean*mean, rstd = rsqrtf(var + 1e-5f);
    __syncthreads();
    #pragma unroll
    for (int i = 0; i < 32; ++i)
        lds[e][j0+i] = fmaxf((acc[i]-mean)*rstd*g1[j0+i]+be1[j0+i], 0.f);
    __syncthreads();
    float acc2[16];
    #pragma unroll
    for (int i = 0; i < 16; ++i) acc2[i] = 0.f;
    const int q0 = jg * 16;
    for (int k4 = 0; k4 < H1C / 4; ++k4) {
        float4 a4 = *(const float4*)&lds[e][k4 * 4];
        float av[4] = {a4.x, a4.y, a4.z, a4.w};
        #pragma unroll
        for (int kk = 0; kk < 4; ++kk) {
            const float a = av[kk];
            const float4* wr = (const float4*)(w2 + (k4 * 4 + kk) * H2C + q0);
            #pragma unroll
            for (int ii = 0; ii < 4; ++ii) {
                float4 wv = wr[ii];
                acc2[ii*4+0] += a*wv.x; acc2[ii*4+1] += a*wv.y; acc2[ii*4+2] += a*wv.z; acc2[ii*4+3] += a*wv.w;
            }
        }
    }
    s1 = 0.f; s2 = 0.f;
    #pragma unroll
    for (int i = 0; i < 16; ++i) { float h = acc2[i] + b2[q0+i]; acc2[i] = h; s1 += h; s2 += h*h; }
    #pragma unroll
    for (int m = 1; m < 8; m <<= 1) { s1 += __shfl_xor(s1, m, 8); s2 += __shfl_xor(s2, m, 8); }
    mean = s1 * (1.f/128.f); var = s2 * (1.f/128.f) - mean*mean; rstd = rsqrtf(var + 1e-5f);
    float zp = 0.f;
    #pragma unroll
    for (int i = 0; i < 16; ++i) {
        float h = fmaxf((acc2[i]-mean)*rstd*g2[q0+i]+be2[q0+i], 0.f);
        zp += h * w3[q0+i];
    }
    #pragma unroll
    for (int m = 1; m < 8; m <<= 1) zp += __shfl_xor(zp, m, 8);
    if (jg == 0) out[row] = 1.f / (1.f + expf(-(zp + b3[0])));
    if (jg == 1) out[ROWS + row] = (row < EPOS) ? 1.f : 0.f;
}

// ===================== host =====================
extern "C" void kernel_launch(void* const* d_in, const int* in_sizes, int n_in,
                              void* d_out, int out_size, void* d_ws, size_t ws_size,
                              hipStream_t stream) {
    const float* x   = (const float*)d_in[0];
    const int*   ei  = (const int*)d_in[1];
    const int*   nei = (const int*)d_in[3];
    const float* w1  = (const float*)d_in[4];
    const float* b1  = (const float*)d_in[5];
    const float* g1  = (const float*)d_in[6];
    const float* be1 = (const float*)d_in[7];
    const float* w2  = (const float*)d_in[8];
    const float* b2  = (const float*)d_in[9];
    const float* g2  = (const float*)d_in[10];
    const float* be2 = (const float*)d_in[11];
    const float* w3  = (const float*)d_in[12];
    const float* b3  = (const float*)d_in[13];
    float* out = (float*)d_out;

    if (ws_size >= WS_NEEDED) {
        bf16* ws = (bf16*)d_ws;
        const int total = XB_N + W1T_N + W2T_N;
        hipLaunchKernelGGL(preconv, dim3((total + 255) / 256), dim3(256), 0, stream,
                           x, w1, w2, ws);
        hipFuncSetAttribute((const void*)lp_mfma,
                            hipFuncAttributeMaxDynamicSharedMemorySize, SMEM_BYTES);
        hipLaunchKernelGGL(lp_mfma, dim3(ROWS / MT), dim3(NTH), SMEM_BYTES, stream,
                           ws + XB_E, ws + W1T_E, ws + W2T_E, ei, nei,
                           b1, g1, be1, b2, g2, be2, w3, b3, out);
    } else {
        hipLaunchKernelGGL(lp_fused, dim3(ROWS / TILE), dim3(256), 0, stream,
                           x, ei, nei, w1, b1, g1, be1, w2, b2, g2, be2, w3, b3, out);
    }
}

// Round 3
// 463.963 us; speedup vs baseline: 59.1963x; 1.2924x over previous
//
#include <hip/hip_runtime.h>
#include <math.h>
#include <stdint.h>

// Problem constants
#define NN    50000
#define EPOS  400000
#define ROWS  800000
#define DIM   128
#define D2    256
#define H1C   256
#define H2C   128
#define MT    64            // edge rows per block
#define NTH   512           // 8 waves

typedef __bf16 bf16;
typedef __bf16 bf16x8 __attribute__((ext_vector_type(8)));
typedef float  f32x4  __attribute__((ext_vector_type(4)));

// ---- workspace element offsets (bf16 elements) ----
#define XB_N   (NN*DIM)             // x as bf16 [node][128]
#define W1F_E  XB_N
#define W1F_N  (H1C*D2)             // w1 in fragment order
#define W2F_E  (XB_N + W1F_N)
#define W2F_N  (H2C*H1C)            // w2 in fragment order
#define WS_NEEDED ((size_t)(XB_N + W1F_N + W2F_N) * 2)

// ---- LDS byte offsets ----
#define AOFF  0        // 32KB: A [64 rows][512B] (src128|dst128 bf16), 3-bit XOR swizzle
#define H1O   32768    // 32KB: h1 [64][256] bf16, same swizzle
#define SCR   65536    // 2KB  LN scratch [64 rows][4 wn]x float2
#define SCR2  67584    // 1KB  z scratch  [64 rows][4 wn]x float
#define SMEM_BYTES 68608

__device__ __forceinline__ void gll16(const void* g, void* l) {
    __builtin_amdgcn_global_load_lds(
        (const __attribute__((address_space(1))) void*)g,
        (__attribute__((address_space(3))) void*)l, 16, 0, 0);
}

// ===================== pre-convert kernel =====================
// Writes: x as bf16; w1/w2 transposed+pre-swizzled into MFMA B-fragment order:
//   elem((t,c,l,j)) = w[k][n], n = t*16 + (l&15), k = c*32 + (l>>4)*8 + j
//   flat = ((t*8 + c)*64 + l)*8 + j   -> per-(t,c) fragment is 1KB contiguous.
__global__ void preconv(const float* __restrict__ x, const float* __restrict__ w1,
                        const float* __restrict__ w2, bf16* __restrict__ ws) {
    int i = blockIdx.x * 256 + threadIdx.x;
    if (i < XB_N) { ws[i] = (bf16)x[i]; return; }
    i -= XB_N;
    if (i < W1F_N) {
        int j = i & 7, l = (i >> 3) & 63, tc = i >> 9;   // tc 0..127
        int t = tc >> 3, c = tc & 7;
        int n = t * 16 + (l & 15);
        int k = c * 32 + (l >> 4) * 8 + j;
        ws[W1F_E + i] = (bf16)w1[k * H1C + n];
        return;
    }
    i -= W1F_N;
    if (i < W2F_N) {
        int j = i & 7, l = (i >> 3) & 63, tc = i >> 9;   // tc 0..63
        int t = tc >> 3, c = tc & 7;
        int n = t * 16 + (l & 15);
        int k = c * 32 + (l >> 4) * 8 + j;
        ws[W2F_E + i] = (bf16)w2[k * H2C + n];
    }
}

// ===================== fused MFMA kernel =====================
__global__ __launch_bounds__(NTH, 4) void lp_mfma2(
    const bf16* __restrict__ xb, const bf16* __restrict__ w1f, const bf16* __restrict__ w2f,
    const int*  __restrict__ ei, const int* __restrict__ nei,
    const float* __restrict__ b1, const float* __restrict__ g1, const float* __restrict__ be1,
    const float* __restrict__ b2, const float* __restrict__ g2, const float* __restrict__ be2,
    const float* __restrict__ w3, const float* __restrict__ b3,
    float* __restrict__ out)
{
    extern __shared__ char smem[];
    const int tid  = threadIdx.x;
    const int lane = tid & 63;
    const int w    = tid >> 6;        // wave 0..7
    const int wm   = w >> 2;          // M half (0..1): 32 rows
    const int wn   = w & 3;           // N quarter
    const int gr0  = blockIdx.x * MT;
    const int l15  = lane & 15;
    const int l4   = lane >> 4;

    // ---- stage A once: [64 rows][512B] = src|dst bf16 rows, swizzled ----
    #pragma unroll
    for (int ii = 0; ii < 4; ++ii) {
        const int i = w * 4 + ii;                         // 0..31, 1KB each
        uint32_t doff = (uint32_t)(i << 10) + (uint32_t)(lane << 4);
        uint32_t loff = doff ^ (((doff >> 9) & 7u) << 4); // inverse swizzle (involution)
        int row = loff >> 9;
        int inb = loff & 511;
        int gr  = gr0 + row;
        int node;
        if (inb < 256) { node = (gr < EPOS) ? ei[gr]        : nei[gr - EPOS]; }
        else           { node = (gr < EPOS) ? ei[EPOS + gr] : nei[gr]; inb -= 256; }
        gll16((const char*)xb + (((size_t)node) << 8) + inb, smem + AOFF + (i << 10));
    }

    // LN1 coeffs (overlap with staging)
    float cb1[4], cg1[4], cbe1[4];
    #pragma unroll
    for (int ni = 0; ni < 4; ++ni) {
        int col = (wn << 6) + (ni << 4) + l15;
        cb1[ni] = b1[col]; cg1[ni] = g1[col]; cbe1[ni] = be1[col];
    }

    uint32_t abase[2], asw[2];
    #pragma unroll
    for (int mi = 0; mi < 2; ++mi) {
        int row = (wm << 5) + (mi << 4) + l15;
        abase[mi] = (uint32_t)row << 9;
        asw[mi]   = (uint32_t)(row & 7) << 4;
    }
    const uint32_t koff = (uint32_t)l4 << 4;

    __syncthreads();

    // ---- GEMM1: feat[64x256] @ w1[256x256], barrier-free ----
    f32x4 acc1[2][4] = {};
    const bf16* bp1 = w1f + ((size_t)wn << 14) + (lane << 3);   // t = wn*4+ni
    #pragma unroll
    for (int c = 0; c < 8; ++c) {
        bf16x8 bfr[4], af[2];
        #pragma unroll
        for (int ni = 0; ni < 4; ++ni)
            bfr[ni] = *(const bf16x8*)(bp1 + ((ni * 8 + c) << 9));
        #pragma unroll
        for (int mi = 0; mi < 2; ++mi)
            af[mi] = *(const bf16x8*)(smem + AOFF + abase[mi] + ((((uint32_t)c << 6) + koff) ^ asw[mi]));
        #pragma unroll
        for (int mi = 0; mi < 2; ++mi)
            #pragma unroll
            for (int ni = 0; ni < 4; ++ni)
                acc1[mi][ni] = __builtin_amdgcn_mfma_f32_16x16x32_bf16(
                    af[mi], bfr[ni], acc1[mi][ni], 0, 0, 0);
    }

    // ---- LN1 + ReLU -> h1 (LDS) ----
    #pragma unroll
    for (int mi = 0; mi < 2; ++mi) {
        #pragma unroll
        for (int j = 0; j < 4; ++j) {
            float s1 = 0.f, s2 = 0.f;
            #pragma unroll
            for (int ni = 0; ni < 4; ++ni) {
                float v = acc1[mi][ni][j] + cb1[ni];
                acc1[mi][ni][j] = v;
                s1 += v; s2 += v * v;
            }
            #pragma unroll
            for (int m = 1; m < 16; m <<= 1) { s1 += __shfl_xor(s1, m); s2 += __shfl_xor(s2, m); }
            if (l15 == 0) {
                int row = (wm << 5) + (mi << 4) + (l4 << 2) + j;
                *(float2*)(smem + SCR + (row << 5) + (wn << 3)) = make_float2(s1, s2);
            }
        }
    }
    __syncthreads();
    #pragma unroll
    for (int mi = 0; mi < 2; ++mi) {
        #pragma unroll
        for (int j = 0; j < 4; ++j) {
            int row = (wm << 5) + (mi << 4) + (l4 << 2) + j;
            f32x4 p0 = *(const f32x4*)(smem + SCR + (row << 5));
            f32x4 p1 = *(const f32x4*)(smem + SCR + (row << 5) + 16);
            float s1 = p0[0] + p0[2] + p1[0] + p1[2];
            float s2 = p0[1] + p0[3] + p1[1] + p1[3];
            float mean = s1 * (1.f / 256.f);
            float var  = s2 * (1.f / 256.f) - mean * mean;
            float rstd = rsqrtf(var + 1e-5f);
            #pragma unroll
            for (int ni = 0; ni < 4; ++ni) {
                int col = (wn << 6) + (ni << 4) + l15;
                float h = (acc1[mi][ni][j] - mean) * rstd * cg1[ni] + cbe1[ni];
                h = fmaxf(h, 0.f);
                uint32_t byte = ((uint32_t)row << 9) + ((uint32_t)col << 1);
                byte ^= ((byte >> 9) & 7u) << 4;
                *(bf16*)(smem + H1O + byte) = (bf16)h;
            }
        }
    }
    __syncthreads();

    // ---- GEMM2: h1[64x256] @ w2[256x128], barrier-free ----
    f32x4 acc2[2][2] = {};
    const bf16* bp2 = w2f + ((size_t)wn << 13) + (lane << 3);   // t = wn*2+ni
    #pragma unroll
    for (int c = 0; c < 8; ++c) {
        bf16x8 b2r[2], a2[2];
        #pragma unroll
        for (int ni = 0; ni < 2; ++ni)
            b2r[ni] = *(const bf16x8*)(bp2 + ((ni * 8 + c) << 9));
        #pragma unroll
        for (int mi = 0; mi < 2; ++mi)
            a2[mi] = *(const bf16x8*)(smem + H1O + abase[mi] + ((((uint32_t)c << 6) + koff) ^ asw[mi]));
        #pragma unroll
        for (int mi = 0; mi < 2; ++mi)
            #pragma unroll
            for (int ni = 0; ni < 2; ++ni)
                acc2[mi][ni] = __builtin_amdgcn_mfma_f32_16x16x32_bf16(
                    a2[mi], b2r[ni], acc2[mi][ni], 0, 0, 0);
    }

    // ---- LN2 + ReLU + w3 dot + sigmoid + labels ----
    float cb2[2], cg2[2], cbe2[2], cw3[2];
    #pragma unroll
    for (int ni = 0; ni < 2; ++ni) {
        int col = (wn << 5) + (ni << 4) + l15;
        cb2[ni] = b2[col]; cg2[ni] = g2[col]; cbe2[ni] = be2[col]; cw3[ni] = w3[col];
    }
    const float b3s = b3[0];

    #pragma unroll
    for (int mi = 0; mi < 2; ++mi) {
        #pragma unroll
        for (int j = 0; j < 4; ++j) {
            float s1 = 0.f, s2 = 0.f;
            #pragma unroll
            for (int ni = 0; ni < 2; ++ni) {
                float v = acc2[mi][ni][j] + cb2[ni];
                acc2[mi][ni][j] = v;
                s1 += v; s2 += v * v;
            }
            #pragma unroll
            for (int m = 1; m < 16; m <<= 1) { s1 += __shfl_xor(s1, m); s2 += __shfl_xor(s2, m); }
            if (l15 == 0) {
                int row = (wm << 5) + (mi << 4) + (l4 << 2) + j;
                *(float2*)(smem + SCR + (row << 5) + (wn << 3)) = make_float2(s1, s2);
            }
        }
    }
    __syncthreads();
    #pragma unroll
    for (int mi = 0; mi < 2; ++mi) {
        #pragma unroll
        for (int j = 0; j < 4; ++j) {
            int row = (wm << 5) + (mi << 4) + (l4 << 2) + j;
            f32x4 p0 = *(const f32x4*)(smem + SCR + (row << 5));
            f32x4 p1 = *(const f32x4*)(smem + SCR + (row << 5) + 16);
            float s1 = p0[0] + p0[2] + p1[0] + p1[2];
            float s2 = p0[1] + p0[3] + p1[1] + p1[3];
            float mean = s1 * (1.f / 128.f);
            float var  = s2 * (1.f / 128.f) - mean * mean;
            float rstd = rsqrtf(var + 1e-5f);
            float zp = 0.f;
            #pragma unroll
            for (int ni = 0; ni < 2; ++ni) {
                float h = (acc2[mi][ni][j] - mean) * rstd * cg2[ni] + cbe2[ni];
                h = fmaxf(h, 0.f);
                zp += h * cw3[ni];
            }
            #pragma unroll
            for (int m = 1; m < 16; m <<= 1) zp += __shfl_xor(zp, m);
            if (l15 == 0)
                *(float*)(smem + SCR2 + (row << 4) + (wn << 2)) = zp;
        }
    }
    __syncthreads();
    #pragma unroll
    for (int mi = 0; mi < 2; ++mi) {
        #pragma unroll
        for (int j = 0; j < 4; ++j) {
            int row = (wm << 5) + (mi << 4) + (l4 << 2) + j;
            if (l15 == 0) {
                f32x4 zv = *(const f32x4*)(smem + SCR2 + (row << 4));
                float z = zv[0] + zv[1] + zv[2] + zv[3] + b3s;
                out[gr0 + row] = 1.f / (1.f + expf(-z));
            }
            if (l15 == 1) {
                int grr = gr0 + row;
                out[ROWS + grr] = (grr < EPOS) ? 1.f : 0.f;
            }
        }
    }
}

// ===================== fallback (round-1 kernel, known correct) =====================
#define TILE  32
#define PAD   264
__global__ __launch_bounds__(256, 4) void lp_fused(
    const float* __restrict__ x, const int* __restrict__ ei, const int* __restrict__ nei,
    const float* __restrict__ w1, const float* __restrict__ b1,
    const float* __restrict__ g1, const float* __restrict__ be1,
    const float* __restrict__ w2, const float* __restrict__ b2,
    const float* __restrict__ g2, const float* __restrict__ be2,
    const float* __restrict__ w3, const float* __restrict__ b3,
    float* __restrict__ out)
{
    __shared__ float lds[TILE][PAD];
    const int t = threadIdx.x, e = t >> 3, jg = t & 7;
    const int row = blockIdx.x * TILE + e;
    {
        int src, dst;
        if (row < EPOS) { src = ei[row];         dst = ei[EPOS + row]; }
        else            { src = nei[row - EPOS]; dst = nei[row]; }
        const float* base = (jg < 4) ? (x + src * DIM + jg * 32) : (x + dst * DIM + (jg - 4) * 32);
        const float4* b4 = (const float4*)base;
        #pragma unroll
        for (int s = 0; s < 8; ++s) *(float4*)&lds[e][jg * 32 + s * 4] = b4[s];
    }
    __syncthreads();
    float acc[32];
    #pragma unroll
    for (int i = 0; i < 32; ++i) acc[i] = 0.f;
    const int j0 = jg * 32;
    for (int k4 = 0; k4 < D2 / 4; ++k4) {
        float4 a4 = *(const float4*)&lds[e][k4 * 4];
        float av[4] = {a4.x, a4.y, a4.z, a4.w};
        #pragma unroll
        for (int kk = 0; kk < 4; ++kk) {
            const float a = av[kk];
            const float4* wr = (const float4*)(w1 + (k4 * 4 + kk) * H1C + j0);
            #pragma unroll
            for (int ii = 0; ii < 8; ++ii) {
                float4 wv = wr[ii];
                acc[ii*4+0] += a*wv.x; acc[ii*4+1] += a*wv.y; acc[ii*4+2] += a*wv.z; acc[ii*4+3] += a*wv.w;
            }
        }
    }
    float s1 = 0.f, s2 = 0.f;
    #pragma unroll
    for (int i = 0; i < 32; ++i) { float h = acc[i] + b1[j0+i]; acc[i] = h; s1 += h; s2 += h*h; }
    #pragma unroll
    for (int m = 1; m < 8; m <<= 1) { s1 += __shfl_xor(s1, m, 8); s2 += __shfl_xor(s2, m, 8); }
    float mean = s1 * (1.f/256.f), var = s2 * (1.f/256.f) - mean*mean, rstd = rsqrtf(var + 1e-5f);
    __syncthreads();
    #pragma unroll
    for (int i = 0; i < 32; ++i)
        lds[e][j0+i] = fmaxf((acc[i]-mean)*rstd*g1[j0+i]+be1[j0+i], 0.f);
    __syncthreads();
    float acc2[16];
    #pragma unroll
    for (int i = 0; i < 16; ++i) acc2[i] = 0.f;
    const int q0 = jg * 16;
    for (int k4 = 0; k4 < H1C / 4; ++k4) {
        float4 a4 = *(const float4*)&lds[e][k4 * 4];
        float av[4] = {a4.x, a4.y, a4.z, a4.w};
        #pragma unroll
        for (int kk = 0; kk < 4; ++kk) {
            const float a = av[kk];
            const float4* wr = (const float4*)(w2 + (k4 * 4 + kk) * H2C + q0);
            #pragma unroll
            for (int ii = 0; ii < 4; ++ii) {
                float4 wv = wr[ii];
                acc2[ii*4+0] += a*wv.x; acc2[ii*4+1] += a*wv.y; acc2[ii*4+2] += a*wv.z; acc2[ii*4+3] += a*wv.w;
            }
        }
    }
    s1 = 0.f; s2 = 0.f;
    #pragma unroll
    for (int i = 0; i < 16; ++i) { float h = acc2[i] + b2[q0+i]; acc2[i] = h; s1 += h; s2 += h*h; }
    #pragma unroll
    for (int m = 1; m < 8; m <<= 1) { s1 += __shfl_xor(s1, m, 8); s2 += __shfl_xor(s2, m, 8); }
    mean = s1 * (1.f/128.f); var = s2 * (1.f/128.f) - mean*mean; rstd = rsqrtf(var + 1e-5f);
    float zp = 0.f;
    #pragma unroll
    for (int i = 0; i < 16; ++i) {
        float h = fmaxf((acc2[i]-mean)*rstd*g2[q0+i]+be2[q0+i], 0.f);
        zp += h * w3[q0+i];
    }
    #pragma unroll
    for (int m = 1; m < 8; m <<= 1) zp += __shfl_xor(zp, m, 8);
    if (jg == 0) out[row] = 1.f / (1.f + expf(-(zp + b3[0])));
    if (jg == 1) out[ROWS + row] = (row < EPOS) ? 1.f : 0.f;
}

// ===================== host =====================
extern "C" void kernel_launch(void* const* d_in, const int* in_sizes, int n_in,
                              void* d_out, int out_size, void* d_ws, size_t ws_size,
                              hipStream_t stream) {
    const float* x   = (const float*)d_in[0];
    const int*   ei  = (const int*)d_in[1];
    const int*   nei = (const int*)d_in[3];
    const float* w1  = (const float*)d_in[4];
    const float* b1  = (const float*)d_in[5];
    const float* g1  = (const float*)d_in[6];
    const float* be1 = (const float*)d_in[7];
    const float* w2  = (const float*)d_in[8];
    const float* b2  = (const float*)d_in[9];
    const float* g2  = (const float*)d_in[10];
    const float* be2 = (const float*)d_in[11];
    const float* w3  = (const float*)d_in[12];
    const float* b3  = (const float*)d_in[13];
    float* out = (float*)d_out;

    if (ws_size >= WS_NEEDED) {
        bf16* ws = (bf16*)d_ws;
        const int total = XB_N + W1F_N + W2F_N;
        hipLaunchKernelGGL(preconv, dim3((total + 255) / 256), dim3(256), 0, stream,
                           x, w1, w2, ws);
        hipFuncSetAttribute((const void*)lp_mfma2,
                            hipFuncAttributeMaxDynamicSharedMemorySize, SMEM_BYTES);
        hipLaunchKernelGGL(lp_mfma2, dim3(ROWS / MT), dim3(NTH), SMEM_BYTES, stream,
                           ws, ws + W1F_E, ws + W2F_E, ei, nei,
                           b1, g1, be1, b2, g2, be2, w3, b3, out);
    } else {
        hipLaunchKernelGGL(lp_fused, dim3(ROWS / TILE), dim3(256), 0, stream,
                           x, ei, nei, w1, b1, g1, be1, w2, b2, g2, be2, w3, b3, out);
    }
}